// Round 6
// baseline (143.609 us; speedup 1.0000x reference)
//
#include <hip/hip_runtime.h>
#include <stdint.h>

#define NB 16384     // rows (B)
#define NC 1000      // classes (C)
#define WPB 4        // waves per block (256 threads)
#define RPW 4        // rows per wave; grid = NB/(WPB*RPW) = 1024
#define NWAVES (NB / RPW)   // 4096 partials (one per wave)

// Issue 8 global_load_dwordx4 (4x target, 4x logits) with NO waitcnt.
// EARLY-CLOBBER outputs: destinations must not alias the address operands
// (async load return would corrupt a later load's address -> page fault).
__device__ __forceinline__ void issue8(const float* ta, const float* tc,
                                       const float* la, const float* lc,
                                       float4& t0, float4& t1, float4& t2, float4& t3,
                                       float4& l0, float4& l1, float4& l2, float4& l3) {
    asm volatile(
        "global_load_dwordx4 %0, %8, off\n\t"
        "global_load_dwordx4 %1, %8, off offset:1024\n\t"
        "global_load_dwordx4 %2, %8, off offset:2048\n\t"
        "global_load_dwordx4 %3, %9, off offset:3072\n\t"
        "global_load_dwordx4 %4, %10, off\n\t"
        "global_load_dwordx4 %5, %10, off offset:1024\n\t"
        "global_load_dwordx4 %6, %10, off offset:2048\n\t"
        "global_load_dwordx4 %7, %11, off offset:3072"
        : "=&v"(t0), "=&v"(t1), "=&v"(t2), "=&v"(t3),
          "=&v"(l0), "=&v"(l1), "=&v"(l2), "=&v"(l3)
        : "v"(ta), "v"(tc), "v"(la), "v"(lc));
}

// Counted wait: at most N vmem ops still outstanding (loads only in this
// kernel's pipelined region -> counts are exact; vmcnt decrements in order).
// sched_barrier(0) stops hipcc hoisting register-only consumers above it.
#define WAIT_VM(N)                                              \
    do {                                                        \
        asm volatile("s_waitcnt vmcnt(" #N ")" ::: "memory");   \
        __builtin_amdgcn_sched_barrier(0);                      \
    } while (0)

// Consume one row held in registers; returns the scaled per-row loss
// (identical in all lanes). No memory traffic inside.
__device__ __forceinline__ float consume_row(
        int lane,
        float4 t0, float4 t1, float4 t2, float4 t3,
        float4 l0, float4 l1, float4 l2, float4 l3) {
    // tail fixup: lanes 58..63 hold duplicates of element 249 at k=3
    if (lane > 57) {
        t3 = make_float4(0.f, 0.f, 0.f, 0.f);             // key never wins
        l3 = make_float4(-1e30f, -1e30f, -1e30f, -1e30f); // hinge -> 0
    }

    // per-lane argmax scan: u64 key = (bits(target)<<32) | ~j
    // targets uniform[0,1) => non-negative => IEEE bit order == value order;
    // tie => larger ~j == smaller j == first occurrence (matches argmax).
    unsigned long long bk = 0ull;
    float bl = 0.f;
    {
        const float4 tq[4] = {t0, t1, t2, t3};
        const float4 lq[4] = {l0, l1, l2, l3};
        #pragma unroll
        for (int k = 0; k < 4; ++k) {
            const float tvals[4] = {tq[k].x, tq[k].y, tq[k].z, tq[k].w};
            const float lvals[4] = {lq[k].x, lq[k].y, lq[k].z, lq[k].w};
            #pragma unroll
            for (int e = 0; e < 4; ++e) {
                const int j = (lane + 64 * k) * 4 + e;
                const unsigned long long c =
                    ((unsigned long long)__float_as_uint(tvals[e]) << 32)
                    | (unsigned int)(~j);
                if (c > bk) { bk = c; bl = lvals[e]; }
            }
        }
    }

    #pragma unroll
    for (int off = 32; off; off >>= 1) {
        const unsigned long long ok = __shfl_xor(bk, off, 64);
        const float              ob = __shfl_xor(bl, off, 64);
        if (ok > bk) { bk = ok; bl = ob; }
    }
    const int   label = (int)(~(unsigned int)bk);
    const float x1    = bl;

    const float inv_pos = 1.0f / (float)(NC - 1);
    float s0 = 0.f, s1 = 0.f;
    {
        const float4 lq[4] = {l0, l1, l2, l3};
        #pragma unroll
        for (int k = 0; k < 4; ++k) {
            const float lvals[4] = {lq[k].x, lq[k].y, lq[k].z, lq[k].w};
            #pragma unroll
            for (int e = 0; e < 4; ++e) {
                const int j = (lane + 64 * k) * 4 + e;
                const float dj = fabsf((float)(label - j));
                float m = dj * inv_pos;
                if (k == 0 && e == 0) m = (lane == 0) ? 1.0f : m;  // j==0 neg term
                const float c = fmaxf(lvals[e] - x1 + m, 0.f);
                if (e & 1) s1 += c; else s0 += c;
            }
        }
    }
    float sum = s0 + s1;
    #pragma unroll
    for (int off = 32; off; off >>= 1)
        sum += __shfl_xor(sum, off, 64);

    return (label != 0) ? sum * (1.0f / (float)NB) : 0.0f;
}

// 4 rows per wave, 2-deep register double-buffer (A/B), counted vmcnt(8):
// the next row's 8 loads stay in flight under the current row's reduce.
// NO stores inside the pipeline (vmcnt counts stay exact); one store/wave.
__global__ __launch_bounds__(256) void ranking_loss_kernel(
        const float* __restrict__ logits,
        const float* __restrict__ target,
        float* __restrict__ partial) {
    const int wave = threadIdx.x >> 6;
    const int lane = threadIdx.x & 63;
    const int widx = blockIdx.x * WPB + wave;     // global wave index
    const int row0 = widx * RPW;

    const int    clane = (lane > 57) ? 57 : lane; // clamp so k=3 stays in row
    const size_t lb = (size_t)lane  * 4;
    const size_t cb = (size_t)clane * 4;

    const float* tr = target + (size_t)row0 * NC;
    const float* lr = logits + (size_t)row0 * NC;

    float4 At0, At1, At2, At3, Al0, Al1, Al2, Al3;
    float4 Bt0, Bt1, Bt2, Bt3, Bl0, Bl1, Bl2, Bl3;

    // prologue: rows 0,1 in flight (16 loads outstanding)
    issue8(tr + lb,      tr + cb,      lr + lb,      lr + cb,
           At0, At1, At2, At3, Al0, Al1, Al2, Al3);
    issue8(tr + NC + lb, tr + NC + cb, lr + NC + lb, lr + NC + cb,
           Bt0, Bt1, Bt2, Bt3, Bl0, Bl1, Bl2, Bl3);

    WAIT_VM(8);   // row0 (A) ready; row1 (B) still in flight
    float acc = consume_row(lane, At0, At1, At2, At3, Al0, Al1, Al2, Al3);

    issue8(tr + 2 * NC + lb, tr + 2 * NC + cb, lr + 2 * NC + lb, lr + 2 * NC + cb,
           At0, At1, At2, At3, Al0, Al1, Al2, Al3);   // row2 -> A
    WAIT_VM(8);   // row1 (B) ready; row2 (A) in flight
    acc += consume_row(lane, Bt0, Bt1, Bt2, Bt3, Bl0, Bl1, Bl2, Bl3);

    issue8(tr + 3 * NC + lb, tr + 3 * NC + cb, lr + 3 * NC + lb, lr + 3 * NC + cb,
           Bt0, Bt1, Bt2, Bt3, Bl0, Bl1, Bl2, Bl3);   // row3 -> B
    WAIT_VM(8);   // row2 (A) ready; row3 (B) in flight
    acc += consume_row(lane, At0, At1, At2, At3, Al0, Al1, Al2, Al3);

    WAIT_VM(0);   // row3 (B) ready
    acc += consume_row(lane, Bt0, Bt1, Bt2, Bt3, Bl0, Bl1, Bl2, Bl3);

    if (lane == 0)
        partial[widx] = acc;   // one store per wave, after all counted waits
}

// Sum 4096 per-wave partials -> out[0]. One block, 256 threads, float4 loads.
__global__ __launch_bounds__(256) void reduce_partials_kernel(
        const float* __restrict__ partial,
        float* __restrict__ out) {
    const int t    = threadIdx.x;
    const int wave = t >> 6;
    const int lane = t & 63;

    float sum = 0.0f;
    const float4* p4 = (const float4*)partial;   // NWAVES/4 = 1024 float4
    #pragma unroll
    for (int i = 0; i < 4; ++i) {
        float4 v = p4[t + i * 256];
        sum += (v.x + v.y) + (v.z + v.w);
    }
    #pragma unroll
    for (int off = 32; off > 0; off >>= 1)
        sum += __shfl_down(sum, off, 64);

    __shared__ float s_sum[4];
    if (lane == 0) s_sum[wave] = sum;
    __syncthreads();
    if (t == 0)
        out[0] = s_sum[0] + s_sum[1] + s_sum[2] + s_sum[3];
}

extern "C" void kernel_launch(void* const* d_in, const int* in_sizes, int n_in,
                              void* d_out, int out_size, void* d_ws, size_t ws_size,
                              hipStream_t stream) {
    const float* logits = (const float*)d_in[0];
    const float* target = (const float*)d_in[1];
    float* out     = (float*)d_out;
    float* partial = (float*)d_ws;   // NWAVES floats = 16 KB scratch

    ranking_loss_kernel<<<NB / (WPB * RPW), 256, 0, stream>>>(logits, target, partial);
    reduce_partials_kernel<<<1, 256, 0, stream>>>(partial, out);
}

// Round 7
// 138.973 us; speedup vs baseline: 1.0334x; 1.0334x over previous
//
#include <hip/hip_runtime.h>
#include <hip/hip_bf16.h>

#define NB 16384     // rows (B)
#define NC 1000      // classes (C)
#define NV (NC / 4)  // float4 loads per row = 250

// Block-per-row, 4 waves. Proven best: 40.7 us kernel, 138.36 us e2e.
// All six structural variants (wave/row, multi-row/wave, forced asm MLP,
// register double-buffer) land at 3.0-3.2 TB/s read -> read-path BW ceiling.
__global__ __launch_bounds__(256) void ranking_loss_kernel(
        const float* __restrict__ logits,
        const float* __restrict__ target,
        float* __restrict__ partial) {
    const int row  = blockIdx.x;
    const int t    = threadIdx.x;
    const int wave = t >> 6;
    const int lane = t & 63;

    const float* __restrict__ trow = target + (size_t)row * NC;
    const float* __restrict__ lrow = logits + (size_t)row * NC;

    // ---- issue both global loads up front (overlap latency) ----
    float4 tv = make_float4(0.f, 0.f, 0.f, 0.f);
    float4 lv = make_float4(0.f, 0.f, 0.f, 0.f);
    const bool active = (t < NV);
    if (active) {
        tv = ((const float4*)trow)[t];
        lv = ((const float4*)lrow)[t];
    }

    // ---- phase 1: argmax(target row), first-index tie-break ----
    float bv = -INFINITY;
    int   bi = NC;  // sentinel > any valid index
    if (active) {
        const int base = t * 4;
        float vals[4] = {tv.x, tv.y, tv.z, tv.w};
        #pragma unroll
        for (int k = 0; k < 4; ++k) {
            if (vals[k] > bv) { bv = vals[k]; bi = base + k; }
        }
    }
    #pragma unroll
    for (int off = 32; off > 0; off >>= 1) {
        float ov = __shfl_down(bv, off, 64);
        int   oi = __shfl_down(bi, off, 64);
        if (ov > bv || (ov == bv && oi < bi)) { bv = ov; bi = oi; }
    }

    __shared__ float s_v[4];
    __shared__ int   s_i[4];
    __shared__ int   s_label;
    __shared__ float s_x1;
    if (lane == 0) { s_v[wave] = bv; s_i[wave] = bi; }
    __syncthreads();
    if (t == 0) {
        float mv = s_v[0]; int mi = s_i[0];
        #pragma unroll
        for (int w = 1; w < 4; ++w) {
            if (s_v[w] > mv || (s_v[w] == mv && s_i[w] < mi)) { mv = s_v[w]; mi = s_i[w]; }
        }
        s_label = mi;
        s_x1 = lrow[mi];   // row is hot in L1/L2
    }
    __syncthreads();
    const int   label = s_label;
    const float x1    = s_x1;

    // ---- phase 2: sum of hinge terms (from registers already loaded) ----
    const float inv_pos = 1.0f / (float)(NC - 1);
    float sum = 0.0f;
    if (active) {
        const int base = t * 4;
        float vals[4] = {lv.x, lv.y, lv.z, lv.w};
        #pragma unroll
        for (int k = 0; k < 4; ++k) {
            const int j = base + k;
            // j==0: neg term, margin = 1.0 (NEG_MARGIN * relu(...), NEG_MARGIN = 1)
            const float margin = (j == 0) ? 1.0f
                                          : fabsf((float)(label - j)) * inv_pos;
            sum += fmaxf(vals[k] - x1 + margin, 0.0f);
        }
    }
    #pragma unroll
    for (int off = 32; off > 0; off >>= 1)
        sum += __shfl_down(sum, off, 64);

    __shared__ float s_sum[4];
    if (lane == 0) s_sum[wave] = sum;
    __syncthreads();
    if (t == 0) {
        const float tot = s_sum[0] + s_sum[1] + s_sum[2] + s_sum[3];
        // plain coalesced store, no atomic; pre-scale by 1/B
        partial[row] = (label != 0) ? tot * (1.0f / (float)NB) : 0.0f;
    }
}

// Sum 16384 partials -> out[0]. One block, 256 threads, float4 loads.
__global__ __launch_bounds__(256) void reduce_partials_kernel(
        const float* __restrict__ partial,
        float* __restrict__ out) {
    const int t    = threadIdx.x;
    const int wave = t >> 6;
    const int lane = t & 63;

    float sum = 0.0f;
    const float4* p4 = (const float4*)partial;
    // NB/4 = 4096 float4; 256 threads -> 16 each, coalesced stride
    #pragma unroll
    for (int i = 0; i < 16; ++i) {
        float4 v = p4[t + i * 256];
        sum += (v.x + v.y) + (v.z + v.w);
    }
    #pragma unroll
    for (int off = 32; off > 0; off >>= 1)
        sum += __shfl_down(sum, off, 64);

    __shared__ float s_sum[4];
    if (lane == 0) s_sum[wave] = sum;
    __syncthreads();
    if (t == 0)
        out[0] = s_sum[0] + s_sum[1] + s_sum[2] + s_sum[3];
}

extern "C" void kernel_launch(void* const* d_in, const int* in_sizes, int n_in,
                              void* d_out, int out_size, void* d_ws, size_t ws_size,
                              hipStream_t stream) {
    const float* logits = (const float*)d_in[0];
    const float* target = (const float*)d_in[1];
    float* out     = (float*)d_out;
    float* partial = (float*)d_ws;   // NB floats = 64 KB scratch

    ranking_loss_kernel<<<NB, 256, 0, stream>>>(logits, target, partial);
    reduce_partials_kernel<<<1, 256, 0, stream>>>(partial, out);
}